// Round 3
// baseline (178.977 us; speedup 1.0000x reference)
//
#include <hip/hip_runtime.h>
#include <hip/hip_bf16.h>

#define NB 4
#define NS 4096
#define ND 1024
#define LN_EPS 1e-5f

// ---------- helpers ----------
__device__ __forceinline__ int pad(int i) { return i + (i >> 4); }  // LDS anti-conflict pad

__device__ __forceinline__ float2 cmul(float2 a, float2 b) {
  return make_float2(a.x * b.x - a.y * b.y, a.x * b.y + a.y * b.x);
}

// reverse 6 base-4 digits of a 12-bit index
__device__ __forceinline__ int rev12(int p) {
  return ((p & 3) << 10) | (((p >> 2) & 3) << 8) | (((p >> 4) & 3) << 6) |
         (((p >> 6) & 3) << 4) | (((p >> 8) & 3) << 2) | ((p >> 10) & 3);
}

// ---- kernel 1: fp32 transpose  x[b][s][d] -> xT[b][d][s]
__global__ __launch_bounds__(256) void ktransF(const float* __restrict__ x,
                                               float* __restrict__ xT) {
  __shared__ float tile[64][65];
  const int b = blockIdx.z;
  const int s0 = blockIdx.x * 64;
  const int d0 = blockIdx.y * 64;
  const int t = threadIdx.x;
  const float* xb = x + (size_t)b * NS * ND;
  #pragma unroll
  for (int p = 0; p < 4; ++p) {
    int r = (t >> 4) + p * 16;
    int c = (t & 15) * 4;
    float4 v = *reinterpret_cast<const float4*>(xb + (size_t)(s0 + r) * ND + (d0 + c));
    tile[r][c] = v.x; tile[r][c + 1] = v.y; tile[r][c + 2] = v.z; tile[r][c + 3] = v.w;
  }
  __syncthreads();
  float* xTb = xT + (size_t)b * ND * NS;
  #pragma unroll
  for (int p = 0; p < 4; ++p) {
    int dr = (t >> 4) + p * 16;
    int sc = (t & 15) * 4;
    float4 o;
    o.x = tile[sc + 0][dr]; o.y = tile[sc + 1][dr];
    o.z = tile[sc + 2][dr]; o.w = tile[sc + 3][dr];
    *reinterpret_cast<float4*>(xTb + (size_t)(d0 + dr) * NS + (s0 + sc)) = o;
  }
}

// ---- kernel 2: per (b, quat-group): packed FFT filter on 4 columns + rotation + LN partials.
// Forward radix-4 DIF (natural -> digit-reversed), filter by fk[rev(p)]/N, inverse radix-4 DIT
// (digit-reversed -> natural). Real kernel => pack 2 real columns as one complex signal.
__global__ __launch_bounds__(256) void kfft(float* __restrict__ xT,
                                            const float* __restrict__ fk,
                                            const float* __restrict__ R,
                                            float* __restrict__ ssum,
                                            float* __restrict__ ssq) {
  __shared__ float2 z[4352];  // 4096 + pad, 34 KiB
  const int t = threadIdx.x;
  const int q = blockIdx.x;   // 0..255 quaternion group
  const int b = blockIdx.y;
  float* base = xT + ((size_t)b * ND + (size_t)q * 4) * NS;
  const float TWO_PI_OVER_N = 1.5339807878856412e-3f;  // 2*pi/4096

  float sA[16], sB[16];  // round-0 filtered columns (c0, c1), s = t + 256k

  #pragma unroll
  for (int rnd = 0; rnd < 2; ++rnd) {
    const float* rowA = base + (size_t)(rnd * 2 + 0) * NS;
    const float* rowB = base + (size_t)(rnd * 2 + 1) * NS;
    // load + pack (z = colA + i colB)
    #pragma unroll
    for (int p = 0; p < 4; ++p) {
      int s = t * 4 + p * 1024;
      float4 va = *reinterpret_cast<const float4*>(rowA + s);
      float4 vb = *reinterpret_cast<const float4*>(rowB + s);
      z[pad(s + 0)] = make_float2(va.x, vb.x);
      z[pad(s + 1)] = make_float2(va.y, vb.y);
      z[pad(s + 2)] = make_float2(va.z, vb.z);
      z[pad(s + 3)] = make_float2(va.w, vb.w);
    }
    // ---- forward DIF: L = 1024, 256, 64, 16, 4, 1
    #pragma unroll
    for (int st = 0; st < 6; ++st) {
      const int lg = 10 - 2 * st;
      const int L = 1 << lg;
      __syncthreads();
      #pragma unroll
      for (int u = 0; u < 4; ++u) {
        const int idx = t + u * 256;
        const int j = idx & (L - 1);
        const int i0 = ((idx >> lg) << (lg + 2)) + j;
        float2 a0 = z[pad(i0)];
        float2 a1 = z[pad(i0 + L)];
        float2 a2 = z[pad(i0 + 2 * L)];
        float2 a3 = z[pad(i0 + 3 * L)];
        float sn, cs;
        __sincosf((float)(j << (10 - lg)) * TWO_PI_OVER_N, &sn, &cs);
        float2 w  = make_float2(cs, -sn);                       // e^{-i theta}
        float2 w2 = make_float2(cs * cs - sn * sn, -2.f * cs * sn);
        float2 w3 = cmul(w2, w);
        float2 t0 = make_float2(a0.x + a2.x, a0.y + a2.y);
        float2 t1 = make_float2(a0.x - a2.x, a0.y - a2.y);
        float2 t2 = make_float2(a1.x + a3.x, a1.y + a3.y);
        float2 t3 = make_float2(a1.x - a3.x, a1.y - a3.y);
        float2 y0 = make_float2(t0.x + t2.x, t0.y + t2.y);
        float2 y1 = make_float2(t1.x + t3.y, t1.y - t3.x);      // t1 + (-i) t3
        float2 y2 = make_float2(t0.x - t2.x, t0.y - t2.y);
        float2 y3 = make_float2(t1.x - t3.y, t1.y + t3.x);      // t1 - (-i) t3
        z[pad(i0)]         = y0;
        z[pad(i0 + L)]     = cmul(y1, w);
        z[pad(i0 + 2 * L)] = cmul(y2, w2);
        z[pad(i0 + 3 * L)] = cmul(y3, w3);
      }
    }
    // ---- filter in digit-reversed domain (fold 1/N)
    __syncthreads();
    #pragma unroll
    for (int p = 0; p < 16; ++p) {
      int pos = t + p * 256;
      float k = fk[rev12(pos)] * (1.0f / 4096.0f);
      float2 v = z[pad(pos)];
      z[pad(pos)] = make_float2(v.x * k, v.y * k);
    }
    // ---- inverse DIT: L = 1, 4, 16, 64, 256, 1024
    #pragma unroll
    for (int st = 0; st < 6; ++st) {
      const int lg = 2 * st;
      const int L = 1 << lg;
      __syncthreads();
      #pragma unroll
      for (int u = 0; u < 4; ++u) {
        const int idx = t + u * 256;
        const int j = idx & (L - 1);
        const int i0 = ((idx >> lg) << (lg + 2)) + j;
        float sn, cs;
        __sincosf((float)(j << (10 - lg)) * TWO_PI_OVER_N, &sn, &cs);
        float2 w  = make_float2(cs, sn);                        // e^{+i theta}
        float2 w2 = make_float2(cs * cs - sn * sn, 2.f * cs * sn);
        float2 w3 = cmul(w2, w);
        float2 a0 = z[pad(i0)];
        float2 a1 = cmul(z[pad(i0 + L)], w);
        float2 a2 = cmul(z[pad(i0 + 2 * L)], w2);
        float2 a3 = cmul(z[pad(i0 + 3 * L)], w3);
        float2 t0 = make_float2(a0.x + a2.x, a0.y + a2.y);
        float2 t1 = make_float2(a0.x - a2.x, a0.y - a2.y);
        float2 t2 = make_float2(a1.x + a3.x, a1.y + a3.y);
        float2 t3 = make_float2(a1.x - a3.x, a1.y - a3.y);
        z[pad(i0)]         = make_float2(t0.x + t2.x, t0.y + t2.y);
        z[pad(i0 + L)]     = make_float2(t1.x - t3.y, t1.y + t3.x);  // t1 + i t3
        z[pad(i0 + 2 * L)] = make_float2(t0.x - t2.x, t0.y - t2.y);
        z[pad(i0 + 3 * L)] = make_float2(t1.x + t3.y, t1.y - t3.x);  // t1 - i t3
      }
    }
    __syncthreads();
    if (rnd == 0) {
      // save filtered columns 0,1 in registers
      #pragma unroll
      for (int k2 = 0; k2 < 16; ++k2) {
        float2 v = z[pad(t + k2 * 256)];
        sA[k2] = v.x; sB[k2] = v.y;
      }
      __syncthreads();  // reads done before round-1 load overwrites
    } else {
      // rotate quaternion (thread-local: same s assignment both rounds), write, LN partials
      const float r00 = R[0],  r01 = R[1],  r02 = R[2],  r03 = R[3];
      const float r10 = R[4],  r11 = R[5],  r12 = R[6],  r13 = R[7];
      const float r20 = R[8],  r21 = R[9],  r22 = R[10], r23 = R[11];
      const float r30 = R[12], r31 = R[13], r32 = R[14], r33 = R[15];
      #pragma unroll
      for (int k2 = 0; k2 < 16; ++k2) {
        int s = t + k2 * 256;
        float2 v = z[pad(s)];
        float c0 = sA[k2], c1 = sB[k2], c2 = v.x, c3 = v.y;
        float o0 = r00 * c0 + r01 * c1 + r02 * c2 + r03 * c3;
        float o1 = r10 * c0 + r11 * c1 + r12 * c2 + r13 * c3;
        float o2 = r20 * c0 + r21 * c1 + r22 * c2 + r23 * c3;
        float o3 = r30 * c0 + r31 * c1 + r32 * c2 + r33 * c3;
        base[s] = o0;
        base[NS + s] = o1;
        base[2 * NS + s] = o2;
        base[3 * NS + s] = o3;
        atomicAdd(&ssum[b * NS + s], o0 + o1 + o2 + o3);
        atomicAdd(&ssq[b * NS + s], o0 * o0 + o1 * o1 + o2 * o2 + o3 * o3);
      }
    }
  }
}

// ---- kernel 3: transpose back + LayerNorm apply  xT[b][d][s] -> out[b][s][d]
__global__ __launch_bounds__(256) void kapply(const float* __restrict__ xT,
                                              const float* __restrict__ ssum,
                                              const float* __restrict__ ssq,
                                              const float* __restrict__ gam,
                                              const float* __restrict__ bet,
                                              float* __restrict__ out) {
  __shared__ float tile[64][65];
  const int b = blockIdx.z;
  const int s0 = blockIdx.x * 64;
  const int d0 = blockIdx.y * 64;
  const int t = threadIdx.x;
  const float* src = xT + ((size_t)b * ND + d0) * NS + s0;
  #pragma unroll
  for (int p = 0; p < 4; ++p) {
    int r = (t >> 4) + p * 16;      // d-local
    int c = (t & 15) * 4;           // s-local
    float4 v = *reinterpret_cast<const float4*>(src + (size_t)r * NS + c);
    tile[r][c] = v.x; tile[r][c + 1] = v.y; tile[r][c + 2] = v.z; tile[r][c + 3] = v.w;
  }
  __syncthreads();
  float* dst = out + ((size_t)b * NS + s0) * ND + d0;
  #pragma unroll
  for (int p = 0; p < 4; ++p) {
    int sr = (t >> 4) + p * 16;     // s-local
    int s = s0 + sr;
    float mean = ssum[b * NS + s] * (1.0f / ND);
    float var = ssq[b * NS + s] * (1.0f / ND) - mean * mean;
    float inv = rsqrtf(var + LN_EPS);
    int dc = (t & 15) * 4;
    float4 g4 = *reinterpret_cast<const float4*>(gam + d0 + dc);
    float4 b4 = *reinterpret_cast<const float4*>(bet + d0 + dc);
    float4 o;
    o.x = (tile[dc + 0][sr] - mean) * inv * g4.x + b4.x;
    o.y = (tile[dc + 1][sr] - mean) * inv * g4.y + b4.y;
    o.z = (tile[dc + 2][sr] - mean) * inv * g4.z + b4.z;
    o.w = (tile[dc + 3][sr] - mean) * inv * g4.w + b4.w;
    *reinterpret_cast<float4*>(dst + (size_t)sr * ND + dc) = o;
  }
}

extern "C" void kernel_launch(void* const* d_in, const int* in_sizes, int n_in,
                              void* d_out, int out_size, void* d_ws, size_t ws_size,
                              hipStream_t stream) {
  const float* x  = (const float*)d_in[0];
  const float* R  = (const float*)d_in[1];
  const float* fk = (const float*)d_in[2];
  const float* gm = (const float*)d_in[3];
  const float* bt = (const float*)d_in[4];
  float* out = (float*)d_out;

  char* ws = (char*)d_ws;
  float* xT   = (float*)ws;                                      // 64 MiB
  float* ssum = (float*)(ws + (size_t)NB * ND * NS * 4);         // 16 KiB
  float* ssq  = ssum + NB * NS;                                  // 16 KiB

  (void)hipMemsetAsync(ssum, 0, (size_t)NB * NS * 2 * sizeof(float), stream);
  ktransF<<<dim3(NS / 64, ND / 64, NB), 256, 0, stream>>>(x, xT);
  kfft<<<dim3(ND / 4, NB), 256, 0, stream>>>(xT, fk, R, ssum, ssq);
  kapply<<<dim3(NS / 64, ND / 64, NB), 256, 0, stream>>>(xT, ssum, ssq, gm, bt, out);
}

// Round 4
// 119.175 us; speedup vs baseline: 1.5018x; 1.5018x over previous
//
#include <hip/hip_runtime.h>
#include <hip/hip_bf16.h>

#define NB 4
#define NS 4096
#define ND 1024
#define LN_EPS 1e-5f

// ---------- helpers ----------
__device__ __forceinline__ int pad(int i) { return i + (i >> 4); }  // LDS anti-conflict pad

__device__ __forceinline__ float2 cadd(float2 a, float2 b) { return make_float2(a.x + b.x, a.y + b.y); }
__device__ __forceinline__ float2 csub(float2 a, float2 b) { return make_float2(a.x - b.x, a.y - b.y); }
__device__ __forceinline__ float2 cmul(float2 a, float2 b) {
  return make_float2(a.x * b.x - a.y * b.y, a.x * b.y + a.y * b.x);
}

// 16-pt DFT in registers, natural order in/out. S=-1 forward (e^{-i}), S=+1 inverse (no 1/N).
template<int S>
__device__ __forceinline__ void dft16(float2* x) {
  const float C1 = 0.9238795325112867f, S1 = 0.3826834323650898f, RT = 0.7071067811865476f;
  const float WC[10] = {1.f, C1, RT, S1, 0.f, -S1, -RT, -C1, -1.f, -C1};
  const float WS[10] = {0.f, S1, RT, C1, 1.f, C1,  RT,  S1,  0.f, -S1};
  // level 1: DFT4 over m1 (stride 4); slot m0+4*r0 holds t[m0][r0]
  #pragma unroll
  for (int m0 = 0; m0 < 4; ++m0) {
    float2 a = x[m0], b = x[m0 + 4], c = x[m0 + 8], d = x[m0 + 12];
    float2 t0 = cadd(a, c), t1 = csub(a, c), t2 = cadd(b, d), t3 = csub(b, d);
    float2 t3i = (S < 0) ? make_float2(t3.y, -t3.x) : make_float2(-t3.y, t3.x);
    x[m0]      = cadd(t0, t2);
    x[m0 + 4]  = cadd(t1, t3i);
    x[m0 + 8]  = csub(t0, t2);
    x[m0 + 12] = csub(t1, t3i);
  }
  // twiddle W16^{S*m0*r0}
  #pragma unroll
  for (int r0 = 1; r0 < 4; ++r0)
    #pragma unroll
    for (int m0 = 1; m0 < 4; ++m0) {
      const int k = m0 * r0;
      const float2 w = make_float2(WC[k], (S < 0) ? -WS[k] : WS[k]);
      x[m0 + 4 * r0] = cmul(x[m0 + 4 * r0], w);
    }
  // level 2: DFT4 over m0; out[r0 + 4*r1]
  float2 y[16];
  #pragma unroll
  for (int r0 = 0; r0 < 4; ++r0) {
    float2 a = x[4 * r0], b = x[4 * r0 + 1], c = x[4 * r0 + 2], d = x[4 * r0 + 3];
    float2 t0 = cadd(a, c), t1 = csub(a, c), t2 = cadd(b, d), t3 = csub(b, d);
    float2 t3i = (S < 0) ? make_float2(t3.y, -t3.x) : make_float2(-t3.y, t3.x);
    y[r0]      = cadd(t0, t2);
    y[r0 + 4]  = cadd(t1, t3i);
    y[r0 + 8]  = csub(t0, t2);
    y[r0 + 12] = csub(t1, t3i);
  }
  #pragma unroll
  for (int i = 0; i < 16; ++i) x[i] = y[i];
}

// ---- kernel 0: fkp[p] = fk[rev16_3digits(p)] / 4096
__global__ void kprep(const float* __restrict__ fk, float* __restrict__ fkp) {
  const int p = blockIdx.x * 256 + threadIdx.x;
  const int rev = ((p & 15) << 8) | (p & 240) | (p >> 8);
  fkp[p] = fk[rev] * (1.0f / 4096.0f);
}

// ---- kernel 1: fp32 transpose  x[b][s][d] -> xT[b][d][s]
__global__ __launch_bounds__(256) void ktransF(const float* __restrict__ x,
                                               float* __restrict__ xT) {
  __shared__ float tile[64][65];
  const int b = blockIdx.z;
  const int s0 = blockIdx.x * 64;
  const int d0 = blockIdx.y * 64;
  const int t = threadIdx.x;
  const float* xb = x + (size_t)b * NS * ND;
  #pragma unroll
  for (int p = 0; p < 4; ++p) {
    int r = (t >> 4) + p * 16;
    int c = (t & 15) * 4;
    float4 v = *reinterpret_cast<const float4*>(xb + (size_t)(s0 + r) * ND + (d0 + c));
    tile[r][c] = v.x; tile[r][c + 1] = v.y; tile[r][c + 2] = v.z; tile[r][c + 3] = v.w;
  }
  __syncthreads();
  float* xTb = xT + (size_t)b * ND * NS;
  #pragma unroll
  for (int p = 0; p < 4; ++p) {
    int dr = (t >> 4) + p * 16;
    int sc = (t & 15) * 4;
    float4 o;
    o.x = tile[sc + 0][dr]; o.y = tile[sc + 1][dr];
    o.z = tile[sc + 2][dr]; o.w = tile[sc + 3][dr];
    *reinterpret_cast<float4*>(xTb + (size_t)(d0 + dr) * NS + (s0 + sc)) = o;
  }
}

// ---- kernel 2: per (b, quat-group): two packed 4096-pt FFT filters (radix-16) run
// concurrently by the two 256-thread halves, then rotation + LN partials.
__global__ __launch_bounds__(512, 4) void kfft(float* __restrict__ xT,
                                               const float* __restrict__ fkp,
                                               const float* __restrict__ R,
                                               float* __restrict__ ssum,
                                               float* __restrict__ ssq) {
  extern __shared__ float2 zdyn[];   // 2 x 4352 float2 = 68 KiB
  const int t = threadIdx.x;
  const int h = t >> 8;              // half: 0 -> cols 0,1 ; 1 -> cols 2,3
  const int tt = t & 255;
  const int q = blockIdx.x;
  const int b = blockIdx.y;
  float* base = xT + ((size_t)b * ND + (size_t)q * 4) * NS;
  float* rowA = base + (size_t)(2 * h) * NS;
  float* rowB = base + (size_t)(2 * h + 1) * NS;
  float2* zz = zdyn + (size_t)h * 4352;
  const float TPON = 1.5339807878856412e-3f;  // 2*pi/4096
  float2 x[16];

  // ---- F1 (L=256): global load (packed) -> DFT16 -> twiddle w_4096^{tt*r} -> LDS
  #pragma unroll
  for (int m = 0; m < 16; ++m)
    x[m] = make_float2(rowA[tt + 256 * m], rowB[tt + 256 * m]);
  dft16<-1>(x);
  {
    float sn, cs; __sincosf((float)tt * TPON, &sn, &cs);
    float2 wb = make_float2(cs, -sn), w = make_float2(1.f, 0.f);
    zz[pad(tt)] = x[0];
    #pragma unroll
    for (int r = 1; r < 16; ++r) { w = cmul(w, wb); zz[pad(tt + 256 * r)] = cmul(x[r], w); }
  }
  __syncthreads();
  // ---- F2 (L=16)
  {
    const int bs = 256 * (tt >> 4) + (tt & 15);
    const int j = tt & 15;
    #pragma unroll
    for (int m = 0; m < 16; ++m) x[m] = zz[pad(bs + 16 * m)];
    dft16<-1>(x);
    float sn, cs; __sincosf((float)j * (TPON * 16.f), &sn, &cs);
    float2 wb = make_float2(cs, -sn), w = make_float2(1.f, 0.f);
    zz[pad(bs)] = x[0];
    #pragma unroll
    for (int r = 1; r < 16; ++r) { w = cmul(w, wb); zz[pad(bs + 16 * r)] = cmul(x[r], w); }
  }
  __syncthreads();
  // ---- F3 (L=1) + filter (digit-reversed domain) + I1 (L=1), all in registers
  {
    const int bs = 16 * tt;
    #pragma unroll
    for (int m = 0; m < 16; ++m) x[m] = zz[pad(bs + m)];
    dft16<-1>(x);
    #pragma unroll
    for (int r4 = 0; r4 < 4; ++r4) {
      float4 kv = *reinterpret_cast<const float4*>(fkp + bs + 4 * r4);
      x[4 * r4 + 0].x *= kv.x; x[4 * r4 + 0].y *= kv.x;
      x[4 * r4 + 1].x *= kv.y; x[4 * r4 + 1].y *= kv.y;
      x[4 * r4 + 2].x *= kv.z; x[4 * r4 + 2].y *= kv.z;
      x[4 * r4 + 3].x *= kv.w; x[4 * r4 + 3].y *= kv.w;
    }
    dft16<1>(x);
    #pragma unroll
    for (int r = 0; r < 16; ++r) zz[pad(bs + r)] = x[r];
  }
  __syncthreads();
  // ---- I2 (L=16): twiddle inputs by w_256^{+j*m}
  {
    const int bs = 256 * (tt >> 4) + (tt & 15);
    const int j = tt & 15;
    float sn, cs; __sincosf((float)j * (TPON * 16.f), &sn, &cs);
    float2 wb = make_float2(cs, sn), w = make_float2(1.f, 0.f);
    x[0] = zz[pad(bs)];
    #pragma unroll
    for (int m = 1; m < 16; ++m) { w = cmul(w, wb); x[m] = cmul(zz[pad(bs + 16 * m)], w); }
    dft16<1>(x);
    #pragma unroll
    for (int r = 0; r < 16; ++r) zz[pad(bs + 16 * r)] = x[r];
  }
  __syncthreads();
  // ---- I3 (L=256): twiddle inputs by w_4096^{+tt*m}; output natural order
  {
    float sn, cs; __sincosf((float)tt * TPON, &sn, &cs);
    float2 wb = make_float2(cs, sn), w = make_float2(1.f, 0.f);
    x[0] = zz[pad(tt)];
    #pragma unroll
    for (int m = 1; m < 16; ++m) { w = cmul(w, wb); x[m] = cmul(zz[pad(tt + 256 * m)], w); }
    dft16<1>(x);
    #pragma unroll
    for (int r = 0; r < 16; ++r) zz[pad(tt + 256 * r)] = x[r];
  }
  __syncthreads();
  // ---- rotation + write-back + LN partials (all 512 threads over s)
  const float r00 = R[0],  r01 = R[1],  r02 = R[2],  r03 = R[3];
  const float r10 = R[4],  r11 = R[5],  r12 = R[6],  r13 = R[7];
  const float r20 = R[8],  r21 = R[9],  r22 = R[10], r23 = R[11];
  const float r30 = R[12], r31 = R[13], r32 = R[14], r33 = R[15];
  #pragma unroll
  for (int k = 0; k < 8; ++k) {
    const int s = t + 512 * k;
    float2 v0 = zdyn[pad(s)];
    float2 v1 = zdyn[4352 + pad(s)];
    float c0 = v0.x, c1 = v0.y, c2 = v1.x, c3 = v1.y;
    float o0 = r00 * c0 + r01 * c1 + r02 * c2 + r03 * c3;
    float o1 = r10 * c0 + r11 * c1 + r12 * c2 + r13 * c3;
    float o2 = r20 * c0 + r21 * c1 + r22 * c2 + r23 * c3;
    float o3 = r30 * c0 + r31 * c1 + r32 * c2 + r33 * c3;
    base[s] = o0;
    base[NS + s] = o1;
    base[2 * NS + s] = o2;
    base[3 * NS + s] = o3;
    atomicAdd(&ssum[b * NS + s], o0 + o1 + o2 + o3);
    atomicAdd(&ssq[b * NS + s], o0 * o0 + o1 * o1 + o2 * o2 + o3 * o3);
  }
}

// ---- kernel 3: transpose back + LayerNorm apply  xT[b][d][s] -> out[b][s][d]
__global__ __launch_bounds__(256) void kapply(const float* __restrict__ xT,
                                              const float* __restrict__ ssum,
                                              const float* __restrict__ ssq,
                                              const float* __restrict__ gam,
                                              const float* __restrict__ bet,
                                              float* __restrict__ out) {
  __shared__ float tile[64][65];
  const int b = blockIdx.z;
  const int s0 = blockIdx.x * 64;
  const int d0 = blockIdx.y * 64;
  const int t = threadIdx.x;
  const float* src = xT + ((size_t)b * ND + d0) * NS + s0;
  #pragma unroll
  for (int p = 0; p < 4; ++p) {
    int r = (t >> 4) + p * 16;      // d-local
    int c = (t & 15) * 4;           // s-local
    float4 v = *reinterpret_cast<const float4*>(src + (size_t)r * NS + c);
    tile[r][c] = v.x; tile[r][c + 1] = v.y; tile[r][c + 2] = v.z; tile[r][c + 3] = v.w;
  }
  __syncthreads();
  float* dst = out + ((size_t)b * NS + s0) * ND + d0;
  #pragma unroll
  for (int p = 0; p < 4; ++p) {
    int sr = (t >> 4) + p * 16;     // s-local
    int s = s0 + sr;
    float mean = ssum[b * NS + s] * (1.0f / ND);
    float var = ssq[b * NS + s] * (1.0f / ND) - mean * mean;
    float inv = rsqrtf(var + LN_EPS);
    int dc = (t & 15) * 4;
    float4 g4 = *reinterpret_cast<const float4*>(gam + d0 + dc);
    float4 b4 = *reinterpret_cast<const float4*>(bet + d0 + dc);
    float4 o;
    o.x = (tile[dc + 0][sr] - mean) * inv * g4.x + b4.x;
    o.y = (tile[dc + 1][sr] - mean) * inv * g4.y + b4.y;
    o.z = (tile[dc + 2][sr] - mean) * inv * g4.z + b4.z;
    o.w = (tile[dc + 3][sr] - mean) * inv * g4.w + b4.w;
    *reinterpret_cast<float4*>(dst + (size_t)sr * ND + dc) = o;
  }
}

extern "C" void kernel_launch(void* const* d_in, const int* in_sizes, int n_in,
                              void* d_out, int out_size, void* d_ws, size_t ws_size,
                              hipStream_t stream) {
  const float* x  = (const float*)d_in[0];
  const float* R  = (const float*)d_in[1];
  const float* fk = (const float*)d_in[2];
  const float* gm = (const float*)d_in[3];
  const float* bt = (const float*)d_in[4];
  float* out = (float*)d_out;

  char* ws = (char*)d_ws;
  float* xT   = (float*)ws;                                          // 64 MiB
  float* ssum = (float*)(ws + (size_t)NB * ND * NS * 4);             // 16 KiB
  float* ssq  = ssum + NB * NS;                                      // 16 KiB
  float* fkp  = ssq + NB * NS;                                       // 16 KiB

  (void)hipFuncSetAttribute((const void*)kfft,
                            hipFuncAttributeMaxDynamicSharedMemorySize, 69632);

  kprep<<<16, 256, 0, stream>>>(fk, fkp);
  (void)hipMemsetAsync(ssum, 0, (size_t)NB * NS * 2 * sizeof(float), stream);
  ktransF<<<dim3(NS / 64, ND / 64, NB), 256, 0, stream>>>(x, xT);
  kfft<<<dim3(ND / 4, NB), 512, 69632, stream>>>(xT, fkp, R, ssum, ssq);
  kapply<<<dim3(NS / 64, ND / 64, NB), 256, 0, stream>>>(xT, ssum, ssq, gm, bt, out);
}